// Round 3
// baseline (276.975 us; speedup 1.0000x reference)
//
#include <hip/hip_runtime.h>
#include <hip/hip_fp16.h>

#define N_NODES  50000
#define N_EDGES  640000
#define N_GRAPHS 500
static constexpr float BN_EPS = 1e-5f;
#define SCAN_NB ((N_NODES + 255) / 256)   // 196 blocks
static constexpr float FIX = 16777216.0f;       // 2^24
static constexpr float FIXINV = 5.9604644775390625e-8f;  // 2^-24
static constexpr float Q16 = 65535.0f;
static constexpr float Q16INV = 1.0f / 65535.0f;

// csr entry: (src<<16) | round(norm*65535). src<50000<2^16; norm<1.
__device__ __forceinline__ float dec_nm(unsigned e) {
    return (float)(e & 0xFFFFu) * Q16INV;
}

// ---------------------------------------------------------------------------
// Packed degree/count: one 64-bit atomic per edge; old value -> seq[] rank.
__global__ void k_degcnt(const int* __restrict__ dst, const float* __restrict__ w,
                         unsigned long long* __restrict__ packed,
                         int* __restrict__ seq, int E) {
    int i = blockIdx.x * blockDim.x + threadIdx.x;
    if (i < E) {
        int d = dst[i];
        unsigned uf = (unsigned)(w[i] * FIX + 0.5f);
        unsigned long long old =
            atomicAdd(&packed[d], (1ULL << 32) | (unsigned long long)uf);
        seq[i] = (int)(old >> 32);
    }
}

// ---------------------------------------------------------------------------
// Fused single-kernel exclusive scan (decoupled lookback) + dinv + goffs +
// bnprep. Replaces scan1/scan2/scan3 (saves 2 launches + one pass over
// packed). Safety: 196 blocks <= 256 CUs -> co-resident; ticket ordering
// means block vbid only spins on earlier tickets (already resident, which
// publish their aggregate unconditionally before any spin). Wave-wide
// lookback: 64 predecessors per window.
static constexpr unsigned long long FLAG_AGG = 1ULL << 62;
static constexpr unsigned long long FLAG_INC = 2ULL << 62;

__global__ __launch_bounds__(256) void k_scanF(
    const unsigned long long* __restrict__ packed,
    unsigned long long* __restrict__ state, unsigned* __restrict__ ticket,
    int* __restrict__ offs, float* __restrict__ dinv,
    const int* __restrict__ batch, int* __restrict__ goffs,
    const float* W1,
    const float* b1, const float* g1, const float* be1, const float* m1, const float* v1,
    const float* b2, const float* g2, const float* be2, const float* m2, const float* v2,
    const float* b3, const float* g3, const float* be3, const float* m3, const float* v3,
    float* kA1, float* kB1, float* kA2, float* kB2, float* kA3, float* kB3,
    int n) {
    __shared__ int vbid_sh;
    __shared__ int part[256];
    __shared__ int prefix_sh;
    int t = threadIdx.x;
    if (t == 0) vbid_sh = (int)atomicAdd(ticket, 1u);
    __syncthreads();
    int vbid = vbid_sh;
    int i = vbid * 256 + t;
    unsigned long long pk = (i < n) ? packed[i] : 0ULL;
    int cnt = (int)(pk >> 32);
    part[t] = cnt;
    __syncthreads();
    for (int off = 1; off < 256; off <<= 1) {
        int u = (t >= off) ? part[t - off] : 0;
        __syncthreads();
        part[t] += u;
        __syncthreads();
    }
    int total = part[255];
    if (t < 64) {
        if (vbid == 0) {
            if (t == 0) {
                __hip_atomic_store(&state[0], FLAG_INC | (unsigned long long)(unsigned)total,
                                   __ATOMIC_RELEASE, __HIP_MEMORY_SCOPE_AGENT);
                prefix_sh = 0;
            }
        } else {
            if (t == 0)
                __hip_atomic_store(&state[vbid], FLAG_AGG | (unsigned long long)(unsigned)total,
                                   __ATOMIC_RELEASE, __HIP_MEMORY_SCOPE_AGENT);
            int run = 0;
            int base = vbid - 1;
            while (true) {
                int j = base - t;
                unsigned long long s;
                if (j >= 0) {
                    s = __hip_atomic_load(&state[j], __ATOMIC_ACQUIRE, __HIP_MEMORY_SCOPE_AGENT);
                    while (s == 0)
                        s = __hip_atomic_load(&state[j], __ATOMIC_ACQUIRE, __HIP_MEMORY_SCOPE_AGENT);
                } else {
                    s = FLAG_INC;   // virtual inclusive prefix 0 below block 0
                }
                bool inc = (s & FLAG_INC) != 0;
                int val = (int)(unsigned)(s & 0xFFFFFFFFULL);
                unsigned long long bal = __ballot(inc);
                int lim = (bal == 0) ? 63 : (int)__builtin_ctzll(bal);
                int contrib = (t <= lim) ? val : 0;
                for (int o = 1; o < 64; o <<= 1) contrib += __shfl_xor(contrib, o);
                run += contrib;
                if (bal != 0) break;
                base -= 64;
            }
            if (t == 0) {
                __hip_atomic_store(&state[vbid],
                                   FLAG_INC | (unsigned long long)(unsigned)(run + total),
                                   __ATOMIC_RELEASE, __HIP_MEMORY_SCOPE_AGENT);
                prefix_sh = run;
            }
        }
    }
    __syncthreads();
    int excl = prefix_sh + part[t] - cnt;
    if (i < n) {
        offs[i] = excl;
        float wdeg = (float)(unsigned)(pk & 0xFFFFFFFFu) * FIXINV;
        dinv[i] = rsqrtf(wdeg + 1.0f);
    }
    if (i == n - 1) offs[n] = N_EDGES;
    // graph range precompute: goffs[g] = lower_bound(batch, g)
    if (i <= N_GRAPHS) {
        int lo = 0, hi = n;
        while (lo < hi) { int m = (lo + hi) >> 1; if (batch[m] < i) lo = m + 1; else hi = m; }
        goffs[i] = lo;
    }
    // bnprep (block 0 only; independent of scan data)
    if (vbid == 0) {
        if (t < 64) {
            float s = g1[t] * rsqrtf(v1[t] + BN_EPS);
            kA1[t] = W1[t] * s;
            kB1[t] = (b1[t] - m1[t]) * s + be1[t];
        }
        if (t < 128) {
            float s2 = g2[t] * rsqrtf(v2[t] + BN_EPS);
            kA2[t] = s2; kB2[t] = (b2[t] - m2[t]) * s2 + be2[t];
            float s3 = g3[t] * rsqrtf(v3[t] + BN_EPS);
            kA3[t] = s3; kB3[t] = (b3[t] - m3[t]) * s3 + be3[t];
        }
    }
}

// Atomic-free CSR fill: pos = offs[dst] + seq[e]. 4-byte packed entry.
// (R1 lesson: do NOT fuse per-edge fp32 atomics here — +24 µs regression.)
__global__ void k_fill(const int* __restrict__ src, const int* __restrict__ dst,
                       const float* __restrict__ w, const float* __restrict__ dinv,
                       const int* __restrict__ offs, const int* __restrict__ seq,
                       unsigned* __restrict__ csr, int E) {
    int e = blockIdx.x * blockDim.x + threadIdx.x;
    if (e < E) {
        int s = src[e], d = dst[e];
        int pos = offs[d] + seq[e];
        float nm = dinv[s] * w[e] * dinv[d];
        unsigned q = (unsigned)(nm * Q16 + 0.5f);
        q = (q > 65535u) ? 65535u : q;
        csr[pos] = ((unsigned)s << 16) | q;
    }
}

// Layer-1 scalar aggregation, 4 lanes/node (quarter-wave) + shfl_xor combine.
__global__ void k_aggx(const int* __restrict__ offs, const unsigned* __restrict__ csr,
                       const float* __restrict__ x, const float* __restrict__ dinv,
                       float* __restrict__ aggx, int n) {
    int gid = blockIdx.x * blockDim.x + threadIdx.x;
    int node = gid >> 2;
    if (node >= n) return;
    int sub = gid & 3;
    float acc = 0.f;
    int e0 = offs[node], e1 = offs[node + 1];
    for (int j = e0 + sub; j < e1; j += 4) {
        unsigned e = csr[j];
        acc += x[e >> 16] * dec_nm(e);
    }
    acc += __shfl_xor(acc, 1);
    acc += __shfl_xor(acc, 2);
    if (sub == 0) {
        float di = dinv[node];
        aggx[node] = acc + x[node] * di * di;
    }
}

// ---------------------------------------------------------------------------
// Fused layer-1-matmul + layer-2 aggregation. 16 threads/node, 4 ch each.
__global__ void k_gather2F(const int* __restrict__ offs, const unsigned* __restrict__ csr,
                           const float* __restrict__ aggx, const float* __restrict__ dinv,
                           const float* __restrict__ kA1, const float* __restrict__ kB1,
                           float* __restrict__ agg2, int n) {
    int gid = blockIdx.x * blockDim.x + threadIdx.x;
    int node = gid >> 4;
    if (node >= n) return;
    int c4 = (gid & 15) * 4;
    float4 wa = *(const float4*)(kA1 + c4);
    float4 wb = *(const float4*)(kB1 + c4);
    float4 acc = {0.f, 0.f, 0.f, 0.f};
    int e0 = offs[node], e1 = offs[node + 1];
    int j = e0;
#define G2F_ACC(av, nmv) { \
        acc.x += nmv * fmaxf(av * wa.x + wb.x, 0.f); \
        acc.y += nmv * fmaxf(av * wa.y + wb.y, 0.f); \
        acc.z += nmv * fmaxf(av * wa.z + wb.z, 0.f); \
        acc.w += nmv * fmaxf(av * wa.w + wb.w, 0.f); }
    for (; j + 7 < e1; j += 8) {
        unsigned e_0 = csr[j];
        unsigned e_1 = csr[j + 1];
        unsigned e_2 = csr[j + 2];
        unsigned e_3 = csr[j + 3];
        unsigned e_4 = csr[j + 4];
        unsigned e_5 = csr[j + 5];
        unsigned e_6 = csr[j + 6];
        unsigned e_7 = csr[j + 7];
        float a0 = aggx[e_0 >> 16];
        float a1 = aggx[e_1 >> 16];
        float a2 = aggx[e_2 >> 16];
        float a3 = aggx[e_3 >> 16];
        float a4 = aggx[e_4 >> 16];
        float a5 = aggx[e_5 >> 16];
        float a6 = aggx[e_6 >> 16];
        float a7 = aggx[e_7 >> 16];
        G2F_ACC(a0, dec_nm(e_0)); G2F_ACC(a1, dec_nm(e_1));
        G2F_ACC(a2, dec_nm(e_2)); G2F_ACC(a3, dec_nm(e_3));
        G2F_ACC(a4, dec_nm(e_4)); G2F_ACC(a5, dec_nm(e_5));
        G2F_ACC(a6, dec_nm(e_6)); G2F_ACC(a7, dec_nm(e_7));
    }
    for (; j < e1; ++j) {
        unsigned e = csr[j];
        float a = aggx[e >> 16];
        G2F_ACC(a, dec_nm(e));
    }
    {
        float di = dinv[node];
        float d2 = di * di;
        float a = aggx[node];
        G2F_ACC(a, d2);
    }
#undef G2F_ACC
    *(float4*)(agg2 + (size_t)node * 64 + c4) = acc;
}

// ---------------------------------------------------------------------------
// Channel-sliced gather (layer 3) from the FP16 layer-2 table (sliced-16
// storage). R3: 4 slices x 32 ch, 4 thr/node, uint4 16B loads — halves the
// load-issue count vs 8x(4x8B) and reads csr 4x not 8x. Slice s blocks land
// on XCDs {s, s+4} (blockIdx%8 rr); each XCD caches one 3.2MB slice span.
__global__ void k_gatherS32(const int* __restrict__ offs, const unsigned* __restrict__ csr,
                            const __half* __restrict__ Hh, const float* __restrict__ dinv,
                            float* __restrict__ aggs, int n) {
    int slice = blockIdx.x & 3;
    int node = (blockIdx.x >> 2) * 64 + threadIdx.x / 4;
    if (node >= n) return;
    int q = threadIdx.x % 4;
    int cb = slice * 32 + q * 8;   // global channel base (8 ch/thread)
    // sliced-16 table addr(c,node) = (c>>4)*(n*16) + node*16 + (c&15);
    // 8 consecutive channels from cb share (cb>>4) and are contiguous.
    const __half* Hb = Hh + (size_t)(cb >> 4) * ((size_t)n * 16) + (cb & 15);
    float acc[8] = {0.f, 0.f, 0.f, 0.f, 0.f, 0.f, 0.f, 0.f};
    int e0 = offs[node], e1 = offs[node + 1];
    int j = e0;
#define GS32_LOAD(ev, rawv) uint4 rawv = *(const uint4*)(Hb + (size_t)((ev) >> 16) * 16)
#define GS32_ACC(rawv, nmv) { \
        __half2 h0 = *(__half2*)&rawv.x; __half2 h1 = *(__half2*)&rawv.y; \
        __half2 h2 = *(__half2*)&rawv.z; __half2 h3 = *(__half2*)&rawv.w; \
        float2 f0 = __half22float2(h0); float2 f1 = __half22float2(h1); \
        float2 f2 = __half22float2(h2); float2 f3 = __half22float2(h3); \
        acc[0] += f0.x * nmv; acc[1] += f0.y * nmv; \
        acc[2] += f1.x * nmv; acc[3] += f1.y * nmv; \
        acc[4] += f2.x * nmv; acc[5] += f2.y * nmv; \
        acc[6] += f3.x * nmv; acc[7] += f3.y * nmv; }
    for (; j + 7 < e1; j += 8) {
        unsigned e_0 = csr[j];
        unsigned e_1 = csr[j + 1];
        unsigned e_2 = csr[j + 2];
        unsigned e_3 = csr[j + 3];
        unsigned e_4 = csr[j + 4];
        unsigned e_5 = csr[j + 5];
        unsigned e_6 = csr[j + 6];
        unsigned e_7 = csr[j + 7];
        GS32_LOAD(e_0, r0); GS32_LOAD(e_1, r1); GS32_LOAD(e_2, r2); GS32_LOAD(e_3, r3);
        GS32_LOAD(e_4, r4); GS32_LOAD(e_5, r5); GS32_LOAD(e_6, r6); GS32_LOAD(e_7, r7);
        GS32_ACC(r0, dec_nm(e_0)); GS32_ACC(r1, dec_nm(e_1));
        GS32_ACC(r2, dec_nm(e_2)); GS32_ACC(r3, dec_nm(e_3));
        GS32_ACC(r4, dec_nm(e_4)); GS32_ACC(r5, dec_nm(e_5));
        GS32_ACC(r6, dec_nm(e_6)); GS32_ACC(r7, dec_nm(e_7));
    }
    for (; j < e1; ++j) {
        unsigned e = csr[j];
        GS32_LOAD(e, rr);
        GS32_ACC(rr, dec_nm(e));
    }
    {
        float di = dinv[node];
        float d2 = di * di;
        GS32_LOAD((unsigned)node << 16, rs);
        GS32_ACC(rs, d2);
    }
#undef GS32_LOAD
#undef GS32_ACC
    float* op = aggs + (size_t)slice * ((size_t)n * 32) + (size_t)node * 32 + q * 8;
    *(float4*)op = make_float4(acc[0], acc[1], acc[2], acc[3]);
    *(float4*)(op + 4) = make_float4(acc[4], acc[5], acc[6], acc[7]);
}

// ---------------------------------------------------------------------------
// Register-tiled matmul: 32 nodes/block, x-tile AND W staged in LDS.
// k4/p loops pinned rolled (#pragma unroll 1) — r6/r8 spilled at 256 VGPR.
// MODE 0 (layer 2): write fp16 table only.
// MODE 1 (layer 3): residual from fp16 table; FUSED mean-pool (block-local
// segmented reduction into LDS, ~128 fp32 atomics/segment into sums[500][128]).
template <int K, int S, int MODE>
__global__ __launch_bounds__(256) void k_mmT(
    const float* __restrict__ Xs, const float* __restrict__ W,
    const float* __restrict__ kA, const float* __restrict__ kB,
    const __half* __restrict__ resh, const int* __restrict__ batch,
    float* __restrict__ sums, __half* __restrict__ outh, int n) {
    constexpr int CS = K / S;
    constexpr int KP = K + 4;
    constexpr int KH = 64;
    constexpr int NPASS = K / KH;
    __shared__ float xl[32 * KP];
    __shared__ float wl[KH * 128];
    int base = blockIdx.x * 32;
    int tid = threadIdx.x;
    constexpr int TOT4 = 32 * K / 4;
    constexpr int SL4 = 32 * CS / 4;
    for (int i = tid; i < TOT4; i += 256) {
        int slice = i / SL4;
        int rem = i - slice * SL4;
        int nl = rem / (CS / 4);
        int off4 = (rem % (CS / 4)) * 4;
        int node = base + nl;
        float4 v = {0.f, 0.f, 0.f, 0.f};
        if (node < n)
            v = *(const float4*)(Xs + (size_t)slice * ((size_t)n * CS) + (size_t)node * CS + off4);
        *(float4*)(&xl[nl * KP + slice * CS + off4]) = v;
    }

    int ct = tid & 31;
    int ng = tid >> 5;
    int c4 = ct * 4;
    float4 acc[4];
#pragma unroll
    for (int i = 0; i < 4; ++i) acc[i] = make_float4(0.f, 0.f, 0.f, 0.f);

#pragma unroll 1
    for (int p = 0; p < NPASS; ++p) {
        if (p > 0) __syncthreads();
        {
            const float4* Wsrc = (const float4*)(W + (size_t)p * KH * 128);
            float4* wl4 = (float4*)wl;
#pragma unroll 1
            for (int i = tid; i < KH * 32; i += 256) wl4[i] = Wsrc[i];
        }
        __syncthreads();

#pragma unroll 1
        for (int k4 = 0; k4 < KH / 4; ++k4) {
            float4 wv0 = *(const float4*)(&wl[(k4 * 4 + 0) * 128 + c4]);
            float4 wv1 = *(const float4*)(&wl[(k4 * 4 + 1) * 128 + c4]);
            float4 wv2 = *(const float4*)(&wl[(k4 * 4 + 2) * 128 + c4]);
            float4 wv3 = *(const float4*)(&wl[(k4 * 4 + 3) * 128 + c4]);
#pragma unroll
            for (int i = 0; i < 4; ++i) {
                float4 xv = *(const float4*)(&xl[(ng * 4 + i) * KP + p * KH + k4 * 4]);
                acc[i].x += xv.x * wv0.x; acc[i].y += xv.x * wv0.y;
                acc[i].z += xv.x * wv0.z; acc[i].w += xv.x * wv0.w;
                acc[i].x += xv.y * wv1.x; acc[i].y += xv.y * wv1.y;
                acc[i].z += xv.y * wv1.z; acc[i].w += xv.y * wv1.w;
                acc[i].x += xv.z * wv2.x; acc[i].y += xv.z * wv2.y;
                acc[i].z += xv.z * wv2.z; acc[i].w += xv.z * wv2.w;
                acc[i].x += xv.w * wv3.x; acc[i].y += xv.w * wv3.y;
                acc[i].z += xv.w * wv3.z; acc[i].w += xv.w * wv3.w;
            }
        }
    }

    float4 ka = *(const float4*)(kA + c4);
    float4 kb = *(const float4*)(kB + c4);
    int bg[4];
#pragma unroll
    for (int i = 0; i < 4; ++i) {
        int node = base + ng * 4 + i;
        bg[i] = -1;
        if (node >= n) continue;
        float4 a = acc[i];
        float4 v;
        v.x = fmaxf(a.x * ka.x + kb.x, 0.f);
        v.y = fmaxf(a.y * ka.y + kb.y, 0.f);
        v.z = fmaxf(a.z * ka.z + kb.z, 0.f);
        v.w = fmaxf(a.w * ka.w + kb.w, 0.f);
        size_t slot = (size_t)(c4 >> 4) * ((size_t)n * 16) + (size_t)node * 16 + (c4 & 15);
        if (MODE == 0) {
            __half2 h01 = __floats2half2_rn(v.x, v.y);
            __half2 h23 = __floats2half2_rn(v.z, v.w);
            uint2 r;
            r.x = *(unsigned*)&h01;
            r.y = *(unsigned*)&h23;
            *(uint2*)(outh + slot) = r;
        } else {
            uint2 rr = *(const uint2*)(resh + slot);
            __half2 p0 = *(__half2*)&rr.x;
            __half2 p1 = *(__half2*)&rr.y;
            float2 f0 = __half22float2(p0);
            float2 f1 = __half22float2(p1);
            v.x += f0.x; v.y += f0.y; v.z += f1.x; v.w += f1.y;
            acc[i] = v;                 // keep final h for pooling
            bg[i] = batch[node];
        }
    }
    if (MODE == 1) {
        __shared__ float pred[8][128];
        int g0 = batch[base];
        int gl = batch[(base + 31 < n) ? (base + 31) : (n - 1)];
        for (int g = g0; g <= gl; ++g) {
            float4 s = make_float4(0.f, 0.f, 0.f, 0.f);
#pragma unroll
            for (int i = 0; i < 4; ++i) {
                if (bg[i] == g) {
                    s.x += acc[i].x; s.y += acc[i].y;
                    s.z += acc[i].z; s.w += acc[i].w;
                }
            }
            __syncthreads();            // pred reusable across g iterations
            *(float4*)(&pred[ng][c4]) = s;
            __syncthreads();
            if (ng < 4) {
                pred[ng][c4 + 0] += pred[ng + 4][c4 + 0];
                pred[ng][c4 + 1] += pred[ng + 4][c4 + 1];
                pred[ng][c4 + 2] += pred[ng + 4][c4 + 2];
                pred[ng][c4 + 3] += pred[ng + 4][c4 + 3];
            }
            __syncthreads();
            if (ng < 2) {
                pred[ng][c4 + 0] += pred[ng + 2][c4 + 0];
                pred[ng][c4 + 1] += pred[ng + 2][c4 + 1];
                pred[ng][c4 + 2] += pred[ng + 2][c4 + 2];
                pred[ng][c4 + 3] += pred[ng + 2][c4 + 3];
            }
            __syncthreads();
            if (ng == 0) {
                atomicAdd(&sums[g * 128 + c4 + 0], pred[0][c4 + 0] + pred[1][c4 + 0]);
                atomicAdd(&sums[g * 128 + c4 + 1], pred[0][c4 + 1] + pred[1][c4 + 1]);
                atomicAdd(&sums[g * 128 + c4 + 2], pred[0][c4 + 2] + pred[1][c4 + 2]);
                atomicAdd(&sums[g * 128 + c4 + 3], pred[0][c4 + 3] + pred[1][c4 + 3]);
            }
        }
    }
}

// ---------------------------------------------------------------------------
// Finalize: out[g] = dot(sums[g]/cnt[g], Wf) + bf. 256KB read — trivial.
__global__ __launch_bounds__(128) void k_final(
    const float* __restrict__ sums, const int* __restrict__ goffs,
    const float* __restrict__ Wf, const float* __restrict__ bf,
    float* __restrict__ out) {
    int g = blockIdx.x;
    int t = threadIdx.x;
    float v = sums[g * 128 + t] * Wf[t];
    for (int o = 32; o > 0; o >>= 1) v += __shfl_down(v, o);
    __shared__ float r[2];
    if (t == 0) r[0] = v;
    if (t == 64) r[1] = v;
    __syncthreads();
    if (t == 0) {
        int cnt = goffs[g + 1] - goffs[g];
        out[g] = (r[0] + r[1]) / fmaxf((float)cnt, 1.f) + bf[0];
    }
}

// ---------------------------------------------------------------------------
extern "C" void kernel_launch(void* const* d_in, const int* in_sizes, int n_in,
                              void* d_out, int out_size, void* d_ws, size_t ws_size,
                              hipStream_t stream) {
    const float* x     = (const float*)d_in[0];
    const int*   ei    = (const int*)d_in[1];
    const int*   src   = ei;
    const int*   dst   = ei + N_EDGES;
    const float* w     = (const float*)d_in[2];
    const int*   batch = (const int*)d_in[3];
    const float* W1 = (const float*)d_in[4];
    const float* b1 = (const float*)d_in[5];
    const float* W2 = (const float*)d_in[6];
    const float* b2 = (const float*)d_in[7];
    const float* W3 = (const float*)d_in[8];
    const float* b3 = (const float*)d_in[9];
    const float* Wf = (const float*)d_in[10];
    const float* bf = (const float*)d_in[11];
    const float* g1 = (const float*)d_in[12];
    const float* be1 = (const float*)d_in[13];
    const float* m1 = (const float*)d_in[14];
    const float* v1 = (const float*)d_in[15];
    const float* g2 = (const float*)d_in[16];
    const float* be2 = (const float*)d_in[17];
    const float* m2 = (const float*)d_in[18];
    const float* v2 = (const float*)d_in[19];
    const float* g3 = (const float*)d_in[20];
    const float* be3 = (const float*)d_in[21];
    const float* m3 = (const float*)d_in[22];
    const float* v3 = (const float*)d_in[23];

    float* out = (float*)d_out;

    // Workspace layout
    float* ws    = (float*)d_ws;
    float* buf2  = ws;                                    // N*128 fp32: agg2 then agg3s
    float* agg2  = buf2;
    unsigned* csr = (unsigned*)(buf2 + (size_t)N_NODES * 128); // E uint
    unsigned long long* packed = (unsigned long long*)(csr + N_EDGES); // N ull
    float* sums  = (float*)(packed + N_NODES);            // G*128
    unsigned long long* state = (unsigned long long*)(sums + N_GRAPHS * 128); // SCAN_NB ull
    unsigned* ticket = (unsigned*)(state + SCAN_NB);      // 4 uint (pad)
    int*   seq   = (int*)(ticket + 4);                    // E
    float* dinv  = (float*)(seq + N_EDGES);               // N
    float* aggx  = dinv + N_NODES;                        // N
    float* kA1   = aggx + N_NODES;                        // 64
    float* kB1   = kA1 + 64;                              // 64
    float* kA2   = kB1 + 64;                              // 128
    float* kB2   = kA2 + 128;                             // 128
    float* kA3   = kB2 + 128;                             // 128
    float* kB3   = kA3 + 128;                             // 128
    int*   offs  = (int*)(kB3 + 128);                     // N+1
    int*   goffs = offs + N_NODES + 1;                    // G+1 (+pad)
    __half* out2h = (__half*)(goffs + 505);               // N*128 fp16 (12.8 MB)

    const int BS = 256;
    auto nb = [](long n) { return (int)((n + 255) / 256); };

    // zero packed + sums + state + ticket in one call (contiguous in ws)
    size_t ms_bytes = (size_t)N_NODES * 8 + (size_t)N_GRAPHS * 128 * 4
                    + (size_t)SCAN_NB * 8 + 16;
    hipMemsetAsync(packed, 0, ms_bytes, stream);

    // --- CSR build + degree norm ---
    k_degcnt<<<nb(N_EDGES), BS, 0, stream>>>(dst, w, packed, seq, N_EDGES);
    k_scanF<<<SCAN_NB, 256, 0, stream>>>(packed, state, ticket, offs, dinv, batch, goffs,
                                         W1, b1, g1, be1, m1, v1, b2, g2, be2, m2, v2,
                                         b3, g3, be3, m3, v3,
                                         kA1, kB1, kA2, kB2, kA3, kB3, N_NODES);
    k_fill<<<nb(N_EDGES), BS, 0, stream>>>(src, dst, w, dinv, offs, seq, csr, N_EDGES);

    // --- Layer 1 aggregate (4 lanes/node) ---
    k_aggx<<<nb((long)N_NODES * 4), BS, 0, stream>>>(offs, csr, x, dinv, aggx, N_NODES);

    // --- Layer 2: fused L1-matmul + aggregate, then matmul -> fp16 ---
    k_gather2F<<<nb((long)N_NODES * 16), BS, 0, stream>>>(
        offs, csr, aggx, dinv, kA1, kB1, agg2, N_NODES);
    k_mmT<64, 1, 0><<<(N_NODES + 31) / 32, BS, 0, stream>>>(
        agg2, W2, kA2, kB2, nullptr, nullptr, nullptr, out2h, N_NODES);

    // --- Layer 3: 32ch-sliced aggregate (uint4 loads), matmul + res + pool ---
    k_gatherS32<<<4 * ((N_NODES + 63) / 64), BS, 0, stream>>>(
        offs, csr, out2h, dinv, buf2, N_NODES);
    k_mmT<128, 4, 1><<<(N_NODES + 31) / 32, BS, 0, stream>>>(
        buf2, W3, kA3, kB3, out2h, batch, sums, nullptr, N_NODES);

    // --- finalize: tiny dot-product over sums ---
    k_final<<<N_GRAPHS, 128, 0, stream>>>(sums, goffs, Wf, bf, out);
}

// Round 4
// 268.953 us; speedup vs baseline: 1.0298x; 1.0298x over previous
//
#include <hip/hip_runtime.h>
#include <hip/hip_fp16.h>

#define N_NODES  50000
#define N_EDGES  640000
#define N_GRAPHS 500
static constexpr float BN_EPS = 1e-5f;
#define SCAN_NB ((N_NODES + 255) / 256)   // 196 blocks
static constexpr float FIX = 16777216.0f;       // 2^24
static constexpr float FIXINV = 5.9604644775390625e-8f;  // 2^-24
static constexpr float Q16 = 65535.0f;
static constexpr float Q16INV = 1.0f / 65535.0f;

// csr entry: (src<<16) | round(norm*65535). src<50000<2^16; norm<1.
__device__ __forceinline__ float dec_nm(unsigned e) {
    return (float)(e & 0xFFFFu) * Q16INV;
}

// ---------------------------------------------------------------------------
// Packed degree/count: one 64-bit atomic per edge; old value -> seq[] rank.
__global__ void k_degcnt(const int* __restrict__ dst, const float* __restrict__ w,
                         unsigned long long* __restrict__ packed,
                         int* __restrict__ seq, int E) {
    int i = blockIdx.x * blockDim.x + threadIdx.x;
    if (i < E) {
        int d = dst[i];
        unsigned uf = (unsigned)(w[i] * FIX + 0.5f);
        unsigned long long old =
            atomicAdd(&packed[d], (1ULL << 32) | (unsigned long long)uf);
        seq[i] = (int)(old >> 32);
    }
}

// ---------------------------------------------------------------------------
// Fused single-kernel exclusive scan (decoupled lookback) + dinv + goffs +
// bnprep. 196 blocks <= 256 CUs -> co-resident; ticket ordering means block
// vbid only spins on earlier tickets (already resident, which publish their
// aggregate unconditionally before any spin). Wave-wide 64-deep lookback.
static constexpr unsigned long long FLAG_AGG = 1ULL << 62;
static constexpr unsigned long long FLAG_INC = 2ULL << 62;

__global__ __launch_bounds__(256) void k_scanF(
    const unsigned long long* __restrict__ packed,
    unsigned long long* __restrict__ state, unsigned* __restrict__ ticket,
    int* __restrict__ offs, float* __restrict__ dinv,
    const int* __restrict__ batch, int* __restrict__ goffs,
    const float* W1,
    const float* b1, const float* g1, const float* be1, const float* m1, const float* v1,
    const float* b2, const float* g2, const float* be2, const float* m2, const float* v2,
    const float* b3, const float* g3, const float* be3, const float* m3, const float* v3,
    float* kA1, float* kB1, float* kA2, float* kB2, float* kA3, float* kB3,
    int n) {
    __shared__ int vbid_sh;
    __shared__ int part[256];
    __shared__ int prefix_sh;
    int t = threadIdx.x;
    if (t == 0) vbid_sh = (int)atomicAdd(ticket, 1u);
    __syncthreads();
    int vbid = vbid_sh;
    int i = vbid * 256 + t;
    unsigned long long pk = (i < n) ? packed[i] : 0ULL;
    int cnt = (int)(pk >> 32);
    part[t] = cnt;
    __syncthreads();
    for (int off = 1; off < 256; off <<= 1) {
        int u = (t >= off) ? part[t - off] : 0;
        __syncthreads();
        part[t] += u;
        __syncthreads();
    }
    int total = part[255];
    if (t < 64) {
        if (vbid == 0) {
            if (t == 0) {
                __hip_atomic_store(&state[0], FLAG_INC | (unsigned long long)(unsigned)total,
                                   __ATOMIC_RELEASE, __HIP_MEMORY_SCOPE_AGENT);
                prefix_sh = 0;
            }
        } else {
            if (t == 0)
                __hip_atomic_store(&state[vbid], FLAG_AGG | (unsigned long long)(unsigned)total,
                                   __ATOMIC_RELEASE, __HIP_MEMORY_SCOPE_AGENT);
            int run = 0;
            int base = vbid - 1;
            while (true) {
                int j = base - t;
                unsigned long long s;
                if (j >= 0) {
                    s = __hip_atomic_load(&state[j], __ATOMIC_ACQUIRE, __HIP_MEMORY_SCOPE_AGENT);
                    while (s == 0)
                        s = __hip_atomic_load(&state[j], __ATOMIC_ACQUIRE, __HIP_MEMORY_SCOPE_AGENT);
                } else {
                    s = FLAG_INC;   // virtual inclusive prefix 0 below block 0
                }
                bool inc = (s & FLAG_INC) != 0;
                int val = (int)(unsigned)(s & 0xFFFFFFFFULL);
                unsigned long long bal = __ballot(inc);
                int lim = (bal == 0) ? 63 : (int)__builtin_ctzll(bal);
                int contrib = (t <= lim) ? val : 0;
                for (int o = 1; o < 64; o <<= 1) contrib += __shfl_xor(contrib, o);
                run += contrib;
                if (bal != 0) break;
                base -= 64;
            }
            if (t == 0) {
                __hip_atomic_store(&state[vbid],
                                   FLAG_INC | (unsigned long long)(unsigned)(run + total),
                                   __ATOMIC_RELEASE, __HIP_MEMORY_SCOPE_AGENT);
                prefix_sh = run;
            }
        }
    }
    __syncthreads();
    int excl = prefix_sh + part[t] - cnt;
    if (i < n) {
        offs[i] = excl;
        float wdeg = (float)(unsigned)(pk & 0xFFFFFFFFu) * FIXINV;
        dinv[i] = rsqrtf(wdeg + 1.0f);
    }
    if (i == n - 1) offs[n] = N_EDGES;
    // graph range precompute: goffs[g] = lower_bound(batch, g)
    if (i <= N_GRAPHS) {
        int lo = 0, hi = n;
        while (lo < hi) { int m = (lo + hi) >> 1; if (batch[m] < i) lo = m + 1; else hi = m; }
        goffs[i] = lo;
    }
    // bnprep (block 0 only; independent of scan data)
    if (vbid == 0) {
        if (t < 64) {
            float s = g1[t] * rsqrtf(v1[t] + BN_EPS);
            kA1[t] = W1[t] * s;
            kB1[t] = (b1[t] - m1[t]) * s + be1[t];
        }
        if (t < 128) {
            float s2 = g2[t] * rsqrtf(v2[t] + BN_EPS);
            kA2[t] = s2; kB2[t] = (b2[t] - m2[t]) * s2 + be2[t];
            float s3 = g3[t] * rsqrtf(v3[t] + BN_EPS);
            kA3[t] = s3; kB3[t] = (b3[t] - m3[t]) * s3 + be3[t];
        }
    }
}

// Atomic-free CSR fill: pos = offs[dst] + seq[e]. 4-byte packed entry.
// (R1 lesson: do NOT fuse per-edge fp32 atomics here — +24 µs regression.)
__global__ void k_fill(const int* __restrict__ src, const int* __restrict__ dst,
                       const float* __restrict__ w, const float* __restrict__ dinv,
                       const int* __restrict__ offs, const int* __restrict__ seq,
                       unsigned* __restrict__ csr, int E) {
    int e = blockIdx.x * blockDim.x + threadIdx.x;
    if (e < E) {
        int s = src[e], d = dst[e];
        int pos = offs[d] + seq[e];
        float nm = dinv[s] * w[e] * dinv[d];
        unsigned q = (unsigned)(nm * Q16 + 0.5f);
        q = (q > 65535u) ? 65535u : q;
        csr[pos] = ((unsigned)s << 16) | q;
    }
}

// Layer-1 scalar aggregation, 4 lanes/node (quarter-wave) + shfl_xor combine.
__global__ void k_aggx(const int* __restrict__ offs, const unsigned* __restrict__ csr,
                       const float* __restrict__ x, const float* __restrict__ dinv,
                       float* __restrict__ aggx, int n) {
    int gid = blockIdx.x * blockDim.x + threadIdx.x;
    int node = gid >> 2;
    if (node >= n) return;
    int sub = gid & 3;
    float acc = 0.f;
    int e0 = offs[node], e1 = offs[node + 1];
    for (int j = e0 + sub; j < e1; j += 4) {
        unsigned e = csr[j];
        acc += x[e >> 16] * dec_nm(e);
    }
    acc += __shfl_xor(acc, 1);
    acc += __shfl_xor(acc, 2);
    if (sub == 0) {
        float di = dinv[node];
        aggx[node] = acc + x[node] * di * di;
    }
}

// ---------------------------------------------------------------------------
// Fused layer-1-matmul + layer-2 aggregation. 16 threads/node, 4 ch each.
__global__ void k_gather2F(const int* __restrict__ offs, const unsigned* __restrict__ csr,
                           const float* __restrict__ aggx, const float* __restrict__ dinv,
                           const float* __restrict__ kA1, const float* __restrict__ kB1,
                           float* __restrict__ agg2, int n) {
    int gid = blockIdx.x * blockDim.x + threadIdx.x;
    int node = gid >> 4;
    if (node >= n) return;
    int c4 = (gid & 15) * 4;
    float4 wa = *(const float4*)(kA1 + c4);
    float4 wb = *(const float4*)(kB1 + c4);
    float4 acc = {0.f, 0.f, 0.f, 0.f};
    int e0 = offs[node], e1 = offs[node + 1];
    int j = e0;
#define G2F_ACC(av, nmv) { \
        acc.x += nmv * fmaxf(av * wa.x + wb.x, 0.f); \
        acc.y += nmv * fmaxf(av * wa.y + wb.y, 0.f); \
        acc.z += nmv * fmaxf(av * wa.z + wb.z, 0.f); \
        acc.w += nmv * fmaxf(av * wa.w + wb.w, 0.f); }
    for (; j + 7 < e1; j += 8) {
        unsigned e_0 = csr[j];
        unsigned e_1 = csr[j + 1];
        unsigned e_2 = csr[j + 2];
        unsigned e_3 = csr[j + 3];
        unsigned e_4 = csr[j + 4];
        unsigned e_5 = csr[j + 5];
        unsigned e_6 = csr[j + 6];
        unsigned e_7 = csr[j + 7];
        float a0 = aggx[e_0 >> 16];
        float a1 = aggx[e_1 >> 16];
        float a2 = aggx[e_2 >> 16];
        float a3 = aggx[e_3 >> 16];
        float a4 = aggx[e_4 >> 16];
        float a5 = aggx[e_5 >> 16];
        float a6 = aggx[e_6 >> 16];
        float a7 = aggx[e_7 >> 16];
        G2F_ACC(a0, dec_nm(e_0)); G2F_ACC(a1, dec_nm(e_1));
        G2F_ACC(a2, dec_nm(e_2)); G2F_ACC(a3, dec_nm(e_3));
        G2F_ACC(a4, dec_nm(e_4)); G2F_ACC(a5, dec_nm(e_5));
        G2F_ACC(a6, dec_nm(e_6)); G2F_ACC(a7, dec_nm(e_7));
    }
    for (; j < e1; ++j) {
        unsigned e = csr[j];
        float a = aggx[e >> 16];
        G2F_ACC(a, dec_nm(e));
    }
    {
        float di = dinv[node];
        float d2 = di * di;
        float a = aggx[node];
        G2F_ACC(a, d2);
    }
#undef G2F_ACC
    *(float4*)(agg2 + (size_t)node * 64 + c4) = acc;
}

// ---------------------------------------------------------------------------
// Channel-sliced gather (layer 3) from the FP16 layer-2 table.
// R4: table is NODE-MAJOR within each 32-ch slice — out2h[slice][node][32]
// (64B-aligned 64B rows). One edge's gather per slice = 4 q-threads reading
// 4x16B CONTIGUOUS = exactly one fully-utilized 64B line (was 2 half-used
// lines). Slice line-footprint 3.2MB -> truly fits the 4MB XCD L2.
__global__ void k_gatherS32(const int* __restrict__ offs, const unsigned* __restrict__ csr,
                            const __half* __restrict__ Hh, const float* __restrict__ dinv,
                            float* __restrict__ aggs, int n) {
    int slice = blockIdx.x & 3;
    int node = (blockIdx.x >> 2) * 64 + threadIdx.x / 4;
    if (node >= n) return;
    int q = threadIdx.x % 4;
    // slice table base + this thread's 8-channel sub-offset (q*8 halfs = 16B)
    const __half* Hb = Hh + (size_t)slice * ((size_t)n * 32) + q * 8;
    float acc[8] = {0.f, 0.f, 0.f, 0.f, 0.f, 0.f, 0.f, 0.f};
    int e0 = offs[node], e1 = offs[node + 1];
    int j = e0;
#define GS32_LOAD(ev, rawv) uint4 rawv = *(const uint4*)(Hb + (size_t)((ev) >> 16) * 32)
#define GS32_ACC(rawv, nmv) { \
        __half2 h0 = *(__half2*)&rawv.x; __half2 h1 = *(__half2*)&rawv.y; \
        __half2 h2 = *(__half2*)&rawv.z; __half2 h3 = *(__half2*)&rawv.w; \
        float2 f0 = __half22float2(h0); float2 f1 = __half22float2(h1); \
        float2 f2 = __half22float2(h2); float2 f3 = __half22float2(h3); \
        acc[0] += f0.x * nmv; acc[1] += f0.y * nmv; \
        acc[2] += f1.x * nmv; acc[3] += f1.y * nmv; \
        acc[4] += f2.x * nmv; acc[5] += f2.y * nmv; \
        acc[6] += f3.x * nmv; acc[7] += f3.y * nmv; }
    for (; j + 7 < e1; j += 8) {
        unsigned e_0 = csr[j];
        unsigned e_1 = csr[j + 1];
        unsigned e_2 = csr[j + 2];
        unsigned e_3 = csr[j + 3];
        unsigned e_4 = csr[j + 4];
        unsigned e_5 = csr[j + 5];
        unsigned e_6 = csr[j + 6];
        unsigned e_7 = csr[j + 7];
        GS32_LOAD(e_0, r0); GS32_LOAD(e_1, r1); GS32_LOAD(e_2, r2); GS32_LOAD(e_3, r3);
        GS32_LOAD(e_4, r4); GS32_LOAD(e_5, r5); GS32_LOAD(e_6, r6); GS32_LOAD(e_7, r7);
        GS32_ACC(r0, dec_nm(e_0)); GS32_ACC(r1, dec_nm(e_1));
        GS32_ACC(r2, dec_nm(e_2)); GS32_ACC(r3, dec_nm(e_3));
        GS32_ACC(r4, dec_nm(e_4)); GS32_ACC(r5, dec_nm(e_5));
        GS32_ACC(r6, dec_nm(e_6)); GS32_ACC(r7, dec_nm(e_7));
    }
    for (; j < e1; ++j) {
        unsigned e = csr[j];
        GS32_LOAD(e, rr);
        GS32_ACC(rr, dec_nm(e));
    }
    {
        float di = dinv[node];
        float d2 = di * di;
        GS32_LOAD((unsigned)node << 16, rs);
        GS32_ACC(rs, d2);
    }
#undef GS32_LOAD
#undef GS32_ACC
    float* op = aggs + (size_t)slice * ((size_t)n * 32) + (size_t)node * 32 + q * 8;
    *(float4*)op = make_float4(acc[0], acc[1], acc[2], acc[3]);
    *(float4*)(op + 4) = make_float4(acc[4], acc[5], acc[6], acc[7]);
}

// ---------------------------------------------------------------------------
// Register-tiled matmul: 32 nodes/block, x-tile AND W staged in LDS.
// k4/p loops pinned rolled (#pragma unroll 1) — r6/r8 spilled at 256 VGPR.
// MODE 0 (layer 2): write fp16 table only (node-major-32 slot layout).
// MODE 1 (layer 3): residual from fp16 table (same layout); FUSED mean-pool.
template <int K, int S, int MODE>
__global__ __launch_bounds__(256) void k_mmT(
    const float* __restrict__ Xs, const float* __restrict__ W,
    const float* __restrict__ kA, const float* __restrict__ kB,
    const __half* __restrict__ resh, const int* __restrict__ batch,
    float* __restrict__ sums, __half* __restrict__ outh, int n) {
    constexpr int CS = K / S;
    constexpr int KP = K + 4;
    constexpr int KH = 64;
    constexpr int NPASS = K / KH;
    __shared__ float xl[32 * KP];
    __shared__ float wl[KH * 128];
    int base = blockIdx.x * 32;
    int tid = threadIdx.x;
    constexpr int TOT4 = 32 * K / 4;
    constexpr int SL4 = 32 * CS / 4;
    for (int i = tid; i < TOT4; i += 256) {
        int slice = i / SL4;
        int rem = i - slice * SL4;
        int nl = rem / (CS / 4);
        int off4 = (rem % (CS / 4)) * 4;
        int node = base + nl;
        float4 v = {0.f, 0.f, 0.f, 0.f};
        if (node < n)
            v = *(const float4*)(Xs + (size_t)slice * ((size_t)n * CS) + (size_t)node * CS + off4);
        *(float4*)(&xl[nl * KP + slice * CS + off4]) = v;
    }

    int ct = tid & 31;
    int ng = tid >> 5;
    int c4 = ct * 4;
    float4 acc[4];
#pragma unroll
    for (int i = 0; i < 4; ++i) acc[i] = make_float4(0.f, 0.f, 0.f, 0.f);

#pragma unroll 1
    for (int p = 0; p < NPASS; ++p) {
        if (p > 0) __syncthreads();
        {
            const float4* Wsrc = (const float4*)(W + (size_t)p * KH * 128);
            float4* wl4 = (float4*)wl;
#pragma unroll 1
            for (int i = tid; i < KH * 32; i += 256) wl4[i] = Wsrc[i];
        }
        __syncthreads();

#pragma unroll 1
        for (int k4 = 0; k4 < KH / 4; ++k4) {
            float4 wv0 = *(const float4*)(&wl[(k4 * 4 + 0) * 128 + c4]);
            float4 wv1 = *(const float4*)(&wl[(k4 * 4 + 1) * 128 + c4]);
            float4 wv2 = *(const float4*)(&wl[(k4 * 4 + 2) * 128 + c4]);
            float4 wv3 = *(const float4*)(&wl[(k4 * 4 + 3) * 128 + c4]);
#pragma unroll
            for (int i = 0; i < 4; ++i) {
                float4 xv = *(const float4*)(&xl[(ng * 4 + i) * KP + p * KH + k4 * 4]);
                acc[i].x += xv.x * wv0.x; acc[i].y += xv.x * wv0.y;
                acc[i].z += xv.x * wv0.z; acc[i].w += xv.x * wv0.w;
                acc[i].x += xv.y * wv1.x; acc[i].y += xv.y * wv1.y;
                acc[i].z += xv.y * wv1.z; acc[i].w += xv.y * wv1.w;
                acc[i].x += xv.z * wv2.x; acc[i].y += xv.z * wv2.y;
                acc[i].z += xv.z * wv2.z; acc[i].w += xv.z * wv2.w;
                acc[i].x += xv.w * wv3.x; acc[i].y += xv.w * wv3.y;
                acc[i].z += xv.w * wv3.z; acc[i].w += xv.w * wv3.w;
            }
        }
    }

    float4 ka = *(const float4*)(kA + c4);
    float4 kb = *(const float4*)(kB + c4);
    int bg[4];
#pragma unroll
    for (int i = 0; i < 4; ++i) {
        int node = base + ng * 4 + i;
        bg[i] = -1;
        if (node >= n) continue;
        float4 a = acc[i];
        float4 v;
        v.x = fmaxf(a.x * ka.x + kb.x, 0.f);
        v.y = fmaxf(a.y * ka.y + kb.y, 0.f);
        v.z = fmaxf(a.z * ka.z + kb.z, 0.f);
        v.w = fmaxf(a.w * ka.w + kb.w, 0.f);
        // node-major-32 slot: table (c4>>5), row node (64B), sub (c4&31)
        size_t slot = (size_t)(c4 >> 5) * ((size_t)n * 32) + (size_t)node * 32 + (c4 & 31);
        if (MODE == 0) {
            __half2 h01 = __floats2half2_rn(v.x, v.y);
            __half2 h23 = __floats2half2_rn(v.z, v.w);
            uint2 r;
            r.x = *(unsigned*)&h01;
            r.y = *(unsigned*)&h23;
            *(uint2*)(outh + slot) = r;
        } else {
            uint2 rr = *(const uint2*)(resh + slot);
            __half2 p0 = *(__half2*)&rr.x;
            __half2 p1 = *(__half2*)&rr.y;
            float2 f0 = __half22float2(p0);
            float2 f1 = __half22float2(p1);
            v.x += f0.x; v.y += f0.y; v.z += f1.x; v.w += f1.y;
            acc[i] = v;                 // keep final h for pooling
            bg[i] = batch[node];
        }
    }
    if (MODE == 1) {
        __shared__ float pred[8][128];
        int g0 = batch[base];
        int gl = batch[(base + 31 < n) ? (base + 31) : (n - 1)];
        for (int g = g0; g <= gl; ++g) {
            float4 s = make_float4(0.f, 0.f, 0.f, 0.f);
#pragma unroll
            for (int i = 0; i < 4; ++i) {
                if (bg[i] == g) {
                    s.x += acc[i].x; s.y += acc[i].y;
                    s.z += acc[i].z; s.w += acc[i].w;
                }
            }
            __syncthreads();            // pred reusable across g iterations
            *(float4*)(&pred[ng][c4]) = s;
            __syncthreads();
            if (ng < 4) {
                pred[ng][c4 + 0] += pred[ng + 4][c4 + 0];
                pred[ng][c4 + 1] += pred[ng + 4][c4 + 1];
                pred[ng][c4 + 2] += pred[ng + 4][c4 + 2];
                pred[ng][c4 + 3] += pred[ng + 4][c4 + 3];
            }
            __syncthreads();
            if (ng < 2) {
                pred[ng][c4 + 0] += pred[ng + 2][c4 + 0];
                pred[ng][c4 + 1] += pred[ng + 2][c4 + 1];
                pred[ng][c4 + 2] += pred[ng + 2][c4 + 2];
                pred[ng][c4 + 3] += pred[ng + 2][c4 + 3];
            }
            __syncthreads();
            if (ng == 0) {
                atomicAdd(&sums[g * 128 + c4 + 0], pred[0][c4 + 0] + pred[1][c4 + 0]);
                atomicAdd(&sums[g * 128 + c4 + 1], pred[0][c4 + 1] + pred[1][c4 + 1]);
                atomicAdd(&sums[g * 128 + c4 + 2], pred[0][c4 + 2] + pred[1][c4 + 2]);
                atomicAdd(&sums[g * 128 + c4 + 3], pred[0][c4 + 3] + pred[1][c4 + 3]);
            }
        }
    }
}

// ---------------------------------------------------------------------------
// Finalize: out[g] = dot(sums[g]/cnt[g], Wf) + bf. 256KB read — trivial.
__global__ __launch_bounds__(128) void k_final(
    const float* __restrict__ sums, const int* __restrict__ goffs,
    const float* __restrict__ Wf, const float* __restrict__ bf,
    float* __restrict__ out) {
    int g = blockIdx.x;
    int t = threadIdx.x;
    float v = sums[g * 128 + t] * Wf[t];
    for (int o = 32; o > 0; o >>= 1) v += __shfl_down(v, o);
    __shared__ float r[2];
    if (t == 0) r[0] = v;
    if (t == 64) r[1] = v;
    __syncthreads();
    if (t == 0) {
        int cnt = goffs[g + 1] - goffs[g];
        out[g] = (r[0] + r[1]) / fmaxf((float)cnt, 1.f) + bf[0];
    }
}

// ---------------------------------------------------------------------------
extern "C" void kernel_launch(void* const* d_in, const int* in_sizes, int n_in,
                              void* d_out, int out_size, void* d_ws, size_t ws_size,
                              hipStream_t stream) {
    const float* x     = (const float*)d_in[0];
    const int*   ei    = (const int*)d_in[1];
    const int*   src   = ei;
    const int*   dst   = ei + N_EDGES;
    const float* w     = (const float*)d_in[2];
    const int*   batch = (const int*)d_in[3];
    const float* W1 = (const float*)d_in[4];
    const float* b1 = (const float*)d_in[5];
    const float* W2 = (const float*)d_in[6];
    const float* b2 = (const float*)d_in[7];
    const float* W3 = (const float*)d_in[8];
    const float* b3 = (const float*)d_in[9];
    const float* Wf = (const float*)d_in[10];
    const float* bf = (const float*)d_in[11];
    const float* g1 = (const float*)d_in[12];
    const float* be1 = (const float*)d_in[13];
    const float* m1 = (const float*)d_in[14];
    const float* v1 = (const float*)d_in[15];
    const float* g2 = (const float*)d_in[16];
    const float* be2 = (const float*)d_in[17];
    const float* m2 = (const float*)d_in[18];
    const float* v2 = (const float*)d_in[19];
    const float* g3 = (const float*)d_in[20];
    const float* be3 = (const float*)d_in[21];
    const float* m3 = (const float*)d_in[22];
    const float* v3 = (const float*)d_in[23];

    float* out = (float*)d_out;

    // Workspace layout
    float* ws    = (float*)d_ws;
    float* buf2  = ws;                                    // N*128 fp32: agg2 then agg3s
    float* agg2  = buf2;
    unsigned* csr = (unsigned*)(buf2 + (size_t)N_NODES * 128); // E uint
    unsigned long long* packed = (unsigned long long*)(csr + N_EDGES); // N ull
    float* sums  = (float*)(packed + N_NODES);            // G*128
    unsigned long long* state = (unsigned long long*)(sums + N_GRAPHS * 128); // SCAN_NB ull
    unsigned* ticket = (unsigned*)(state + SCAN_NB);      // 4 uint (pad)
    int*   seq   = (int*)(ticket + 4);                    // E
    float* dinv  = (float*)(seq + N_EDGES);               // N
    float* aggx  = dinv + N_NODES;                        // N
    float* kA1   = aggx + N_NODES;                        // 64
    float* kB1   = kA1 + 64;                              // 64
    float* kA2   = kB1 + 64;                              // 128
    float* kB2   = kA2 + 128;                             // 128
    float* kA3   = kB2 + 128;                             // 128
    float* kB3   = kA3 + 128;                             // 128
    int*   offs  = (int*)(kB3 + 128);                     // N+1
    int*   goffs = offs + N_NODES + 1;                    // G+1 (+pad)
    // out2h: N*128 fp16 table, 64B-aligned so each 64B node-row is one line
    uintptr_t oh = (uintptr_t)(goffs + 505);
    oh = (oh + 63) & ~(uintptr_t)63;
    __half* out2h = (__half*)oh;                          // 12.8 MB

    const int BS = 256;
    auto nb = [](long n) { return (int)((n + 255) / 256); };

    // zero packed + sums + state + ticket in one call (contiguous in ws)
    size_t ms_bytes = (size_t)N_NODES * 8 + (size_t)N_GRAPHS * 128 * 4
                    + (size_t)SCAN_NB * 8 + 16;
    hipMemsetAsync(packed, 0, ms_bytes, stream);

    // --- CSR build + degree norm ---
    k_degcnt<<<nb(N_EDGES), BS, 0, stream>>>(dst, w, packed, seq, N_EDGES);
    k_scanF<<<SCAN_NB, 256, 0, stream>>>(packed, state, ticket, offs, dinv, batch, goffs,
                                         W1, b1, g1, be1, m1, v1, b2, g2, be2, m2, v2,
                                         b3, g3, be3, m3, v3,
                                         kA1, kB1, kA2, kB2, kA3, kB3, N_NODES);
    k_fill<<<nb(N_EDGES), BS, 0, stream>>>(src, dst, w, dinv, offs, seq, csr, N_EDGES);

    // --- Layer 1 aggregate (4 lanes/node) ---
    k_aggx<<<nb((long)N_NODES * 4), BS, 0, stream>>>(offs, csr, x, dinv, aggx, N_NODES);

    // --- Layer 2: fused L1-matmul + aggregate, then matmul -> fp16 table ---
    k_gather2F<<<nb((long)N_NODES * 16), BS, 0, stream>>>(
        offs, csr, aggx, dinv, kA1, kB1, agg2, N_NODES);
    k_mmT<64, 1, 0><<<(N_NODES + 31) / 32, BS, 0, stream>>>(
        agg2, W2, kA2, kB2, nullptr, nullptr, nullptr, out2h, N_NODES);

    // --- Layer 3: node-major-32 sliced aggregate (1 line/edge/slice), ---
    // --- matmul + residual + fused pool ---
    k_gatherS32<<<4 * ((N_NODES + 63) / 64), BS, 0, stream>>>(
        offs, csr, out2h, dinv, buf2, N_NODES);
    k_mmT<128, 4, 1><<<(N_NODES + 31) / 32, BS, 0, stream>>>(
        buf2, W3, kA3, kB3, out2h, batch, sums, nullptr, N_NODES);

    // --- finalize: tiny dot-product over sums ---
    k_final<<<N_GRAPHS, 128, 0, stream>>>(sums, goffs, Wf, bf, out);
}

// Round 5
// 242.780 us; speedup vs baseline: 1.1408x; 1.1078x over previous
//
#include <hip/hip_runtime.h>
#include <hip/hip_fp16.h>

#define N_NODES  50000
#define N_EDGES  640000
#define N_GRAPHS 500
static constexpr float BN_EPS = 1e-5f;
#define SCAN_NB ((N_NODES + 255) / 256)   // 196 blocks
static constexpr float FIX = 16777216.0f;       // 2^24
static constexpr float FIXINV = 5.9604644775390625e-8f;  // 2^-24
static constexpr float Q16 = 65535.0f;
static constexpr float Q16INV = 1.0f / 65535.0f;

typedef _Float16 f16x8 __attribute__((ext_vector_type(8)));
typedef float f32x4 __attribute__((ext_vector_type(4)));

// csr entry: (src<<16) | round(norm*65535). src<50000<2^16; norm<1.
__device__ __forceinline__ float dec_nm(unsigned e) {
    return (float)(e & 0xFFFFu) * Q16INV;
}

// ---------------------------------------------------------------------------
// Packed degree/count: one 64-bit atomic per edge; old value -> seq[] rank.
__global__ void k_degcnt(const int* __restrict__ dst, const float* __restrict__ w,
                         unsigned long long* __restrict__ packed,
                         int* __restrict__ seq, int E) {
    int i = blockIdx.x * blockDim.x + threadIdx.x;
    if (i < E) {
        int d = dst[i];
        unsigned uf = (unsigned)(w[i] * FIX + 0.5f);
        unsigned long long old =
            atomicAdd(&packed[d], (1ULL << 32) | (unsigned long long)uf);
        seq[i] = (int)(old >> 32);
    }
}

// ---------------------------------------------------------------------------
// Fused single-kernel exclusive scan (decoupled lookback) + dinv + goffs +
// bnprep (vbid 0) + W3 fragment pre-swizzle (vbid 1). 196 blocks co-resident;
// ticket ordering -> only spin on already-resident earlier blocks.
static constexpr unsigned long long FLAG_AGG = 1ULL << 62;
static constexpr unsigned long long FLAG_INC = 2ULL << 62;

__global__ __launch_bounds__(256) void k_scanF(
    const unsigned long long* __restrict__ packed,
    unsigned long long* __restrict__ state, unsigned* __restrict__ ticket,
    int* __restrict__ offs, float* __restrict__ dinv,
    const int* __restrict__ batch, int* __restrict__ goffs,
    const float* W1,
    const float* b1, const float* g1, const float* be1, const float* m1, const float* v1,
    const float* b2, const float* g2, const float* be2, const float* m2, const float* v2,
    const float* b3, const float* g3, const float* be3, const float* m3, const float* v3,
    float* kA1, float* kB1, float* kA2, float* kB2, float* kA3, float* kB3,
    const float* __restrict__ W3, __half* __restrict__ W3s,
    int n) {
    __shared__ int vbid_sh;
    __shared__ int part[256];
    __shared__ int prefix_sh;
    int t = threadIdx.x;
    if (t == 0) vbid_sh = (int)atomicAdd(ticket, 1u);
    __syncthreads();
    int vbid = vbid_sh;
    int i = vbid * 256 + t;
    unsigned long long pk = (i < n) ? packed[i] : 0ULL;
    int cnt = (int)(pk >> 32);
    part[t] = cnt;
    __syncthreads();
    for (int off = 1; off < 256; off <<= 1) {
        int u = (t >= off) ? part[t - off] : 0;
        __syncthreads();
        part[t] += u;
        __syncthreads();
    }
    int total = part[255];
    if (t < 64) {
        if (vbid == 0) {
            if (t == 0) {
                __hip_atomic_store(&state[0], FLAG_INC | (unsigned long long)(unsigned)total,
                                   __ATOMIC_RELEASE, __HIP_MEMORY_SCOPE_AGENT);
                prefix_sh = 0;
            }
        } else {
            if (t == 0)
                __hip_atomic_store(&state[vbid], FLAG_AGG | (unsigned long long)(unsigned)total,
                                   __ATOMIC_RELEASE, __HIP_MEMORY_SCOPE_AGENT);
            int run = 0;
            int base = vbid - 1;
            while (true) {
                int j = base - t;
                unsigned long long s;
                if (j >= 0) {
                    s = __hip_atomic_load(&state[j], __ATOMIC_ACQUIRE, __HIP_MEMORY_SCOPE_AGENT);
                    while (s == 0)
                        s = __hip_atomic_load(&state[j], __ATOMIC_ACQUIRE, __HIP_MEMORY_SCOPE_AGENT);
                } else {
                    s = FLAG_INC;   // virtual inclusive prefix 0 below block 0
                }
                bool inc = (s & FLAG_INC) != 0;
                int val = (int)(unsigned)(s & 0xFFFFFFFFULL);
                unsigned long long bal = __ballot(inc);
                int lim = (bal == 0) ? 63 : (int)__builtin_ctzll(bal);
                int contrib = (t <= lim) ? val : 0;
                for (int o = 1; o < 64; o <<= 1) contrib += __shfl_xor(contrib, o);
                run += contrib;
                if (bal != 0) break;
                base -= 64;
            }
            if (t == 0) {
                __hip_atomic_store(&state[vbid],
                                   FLAG_INC | (unsigned long long)(unsigned)(run + total),
                                   __ATOMIC_RELEASE, __HIP_MEMORY_SCOPE_AGENT);
                prefix_sh = run;
            }
        }
    }
    __syncthreads();
    int excl = prefix_sh + part[t] - cnt;
    if (i < n) {
        offs[i] = excl;
        float wdeg = (float)(unsigned)(pk & 0xFFFFFFFFu) * FIXINV;
        dinv[i] = rsqrtf(wdeg + 1.0f);
    }
    if (i == n - 1) offs[n] = N_EDGES;
    // graph range precompute: goffs[g] = lower_bound(batch, g)
    if (i <= N_GRAPHS) {
        int lo = 0, hi = n;
        while (lo < hi) { int m = (lo + hi) >> 1; if (batch[m] < i) lo = m + 1; else hi = m; }
        goffs[i] = lo;
    }
    // bnprep (block 0 only; independent of scan data)
    if (vbid == 0) {
        if (t < 64) {
            float s = g1[t] * rsqrtf(v1[t] + BN_EPS);
            kA1[t] = W1[t] * s;
            kB1[t] = (b1[t] - m1[t]) * s + be1[t];
        }
        if (t < 128) {
            float s2 = g2[t] * rsqrtf(v2[t] + BN_EPS);
            kA2[t] = s2; kB2[t] = (b2[t] - m2[t]) * s2 + be2[t];
            float s3 = g3[t] * rsqrtf(v3[t] + BN_EPS);
            kA3[t] = s3; kB3[t] = (b3[t] - m3[t]) * s3 + be3[t];
        }
    }
    // W3 fp16 B-fragment pre-swizzle (vbid 1): W3s[nt][ks][lane][8] =
    // W3[ks*32 + (lane>>4)*8 + j][nt*16 + (lane&15)]  (8 k-contiguous per lane)
    if (vbid == 1) {
        for (int idx = t; idx < 2048; idx += 256) {
            int nt = idx >> 8;
            int ks = (idx >> 6) & 3;
            int lane = idx & 63;
            int col = nt * 16 + (lane & 15);
            int kb = ks * 32 + (lane >> 4) * 8;
            uint4 uv;
            unsigned* up = &uv.x;
            for (int j2 = 0; j2 < 4; ++j2) {
                __half2 p = __floats2half2_rn(W3[(size_t)(kb + 2 * j2) * 128 + col],
                                              W3[(size_t)(kb + 2 * j2 + 1) * 128 + col]);
                up[j2] = *(unsigned*)&p;
            }
            *(uint4*)(W3s + (size_t)idx * 8) = uv;
        }
    }
}

// Atomic-free CSR fill: pos = offs[dst] + seq[e]. 4-byte packed entry.
// (R1 lesson: do NOT fuse per-edge fp32 atomics here — +24 µs regression.)
__global__ void k_fill(const int* __restrict__ src, const int* __restrict__ dst,
                       const float* __restrict__ w, const float* __restrict__ dinv,
                       const int* __restrict__ offs, const int* __restrict__ seq,
                       unsigned* __restrict__ csr, int E) {
    int e = blockIdx.x * blockDim.x + threadIdx.x;
    if (e < E) {
        int s = src[e], d = dst[e];
        int pos = offs[d] + seq[e];
        float nm = dinv[s] * w[e] * dinv[d];
        unsigned q = (unsigned)(nm * Q16 + 0.5f);
        q = (q > 65535u) ? 65535u : q;
        csr[pos] = ((unsigned)s << 16) | q;
    }
}

// Layer-1 scalar aggregation, 4 lanes/node (quarter-wave) + shfl_xor combine.
__global__ void k_aggx(const int* __restrict__ offs, const unsigned* __restrict__ csr,
                       const float* __restrict__ x, const float* __restrict__ dinv,
                       float* __restrict__ aggx, int n) {
    int gid = blockIdx.x * blockDim.x + threadIdx.x;
    int node = gid >> 2;
    if (node >= n) return;
    int sub = gid & 3;
    float acc = 0.f;
    int e0 = offs[node], e1 = offs[node + 1];
    for (int j = e0 + sub; j < e1; j += 4) {
        unsigned e = csr[j];
        acc += x[e >> 16] * dec_nm(e);
    }
    acc += __shfl_xor(acc, 1);
    acc += __shfl_xor(acc, 2);
    if (sub == 0) {
        float di = dinv[node];
        aggx[node] = acc + x[node] * di * di;
    }
}

// ---------------------------------------------------------------------------
// Fused layer-1-matmul + layer-2 aggregation. 16 threads/node, 4 ch each.
__global__ void k_gather2F(const int* __restrict__ offs, const unsigned* __restrict__ csr,
                           const float* __restrict__ aggx, const float* __restrict__ dinv,
                           const float* __restrict__ kA1, const float* __restrict__ kB1,
                           float* __restrict__ agg2, int n) {
    int gid = blockIdx.x * blockDim.x + threadIdx.x;
    int node = gid >> 4;
    if (node >= n) return;
    int c4 = (gid & 15) * 4;
    float4 wa = *(const float4*)(kA1 + c4);
    float4 wb = *(const float4*)(kB1 + c4);
    float4 acc = {0.f, 0.f, 0.f, 0.f};
    int e0 = offs[node], e1 = offs[node + 1];
    int j = e0;
#define G2F_ACC(av, nmv) { \
        acc.x += nmv * fmaxf(av * wa.x + wb.x, 0.f); \
        acc.y += nmv * fmaxf(av * wa.y + wb.y, 0.f); \
        acc.z += nmv * fmaxf(av * wa.z + wb.z, 0.f); \
        acc.w += nmv * fmaxf(av * wa.w + wb.w, 0.f); }
    for (; j + 7 < e1; j += 8) {
        unsigned e_0 = csr[j];
        unsigned e_1 = csr[j + 1];
        unsigned e_2 = csr[j + 2];
        unsigned e_3 = csr[j + 3];
        unsigned e_4 = csr[j + 4];
        unsigned e_5 = csr[j + 5];
        unsigned e_6 = csr[j + 6];
        unsigned e_7 = csr[j + 7];
        float a0 = aggx[e_0 >> 16];
        float a1 = aggx[e_1 >> 16];
        float a2 = aggx[e_2 >> 16];
        float a3 = aggx[e_3 >> 16];
        float a4 = aggx[e_4 >> 16];
        float a5 = aggx[e_5 >> 16];
        float a6 = aggx[e_6 >> 16];
        float a7 = aggx[e_7 >> 16];
        G2F_ACC(a0, dec_nm(e_0)); G2F_ACC(a1, dec_nm(e_1));
        G2F_ACC(a2, dec_nm(e_2)); G2F_ACC(a3, dec_nm(e_3));
        G2F_ACC(a4, dec_nm(e_4)); G2F_ACC(a5, dec_nm(e_5));
        G2F_ACC(a6, dec_nm(e_6)); G2F_ACC(a7, dec_nm(e_7));
    }
    for (; j < e1; ++j) {
        unsigned e = csr[j];
        float a = aggx[e >> 16];
        G2F_ACC(a, dec_nm(e));
    }
    {
        float di = dinv[node];
        float d2 = di * di;
        float a = aggx[node];
        G2F_ACC(a, d2);
    }
#undef G2F_ACC
    *(float4*)(agg2 + (size_t)node * 64 + c4) = acc;
}

// ---------------------------------------------------------------------------
// Channel-sliced gather (layer 3). R4 layout kept: table node-major per
// 32-ch slice, one fully-utilized 64B line per edge per slice.
// R5: output fp16 (A-fragment-ready for the MFMA matmul; numerically
// identical to fp32-store-then-round since the matmul input is f16 anyway).
__global__ void k_gatherS32(const int* __restrict__ offs, const unsigned* __restrict__ csr,
                            const __half* __restrict__ Hh, const float* __restrict__ dinv,
                            __half* __restrict__ aggs, int n) {
    int slice = blockIdx.x & 3;
    int node = (blockIdx.x >> 2) * 64 + threadIdx.x / 4;
    if (node >= n) return;
    int q = threadIdx.x % 4;
    const __half* Hb = Hh + (size_t)slice * ((size_t)n * 32) + q * 8;
    float acc[8] = {0.f, 0.f, 0.f, 0.f, 0.f, 0.f, 0.f, 0.f};
    int e0 = offs[node], e1 = offs[node + 1];
    int j = e0;
#define GS32_LOAD(ev, rawv) uint4 rawv = *(const uint4*)(Hb + (size_t)((ev) >> 16) * 32)
#define GS32_ACC(rawv, nmv) { \
        __half2 h0 = *(__half2*)&rawv.x; __half2 h1 = *(__half2*)&rawv.y; \
        __half2 h2 = *(__half2*)&rawv.z; __half2 h3 = *(__half2*)&rawv.w; \
        float2 f0 = __half22float2(h0); float2 f1 = __half22float2(h1); \
        float2 f2 = __half22float2(h2); float2 f3 = __half22float2(h3); \
        acc[0] += f0.x * nmv; acc[1] += f0.y * nmv; \
        acc[2] += f1.x * nmv; acc[3] += f1.y * nmv; \
        acc[4] += f2.x * nmv; acc[5] += f2.y * nmv; \
        acc[6] += f3.x * nmv; acc[7] += f3.y * nmv; }
    for (; j + 7 < e1; j += 8) {
        unsigned e_0 = csr[j];
        unsigned e_1 = csr[j + 1];
        unsigned e_2 = csr[j + 2];
        unsigned e_3 = csr[j + 3];
        unsigned e_4 = csr[j + 4];
        unsigned e_5 = csr[j + 5];
        unsigned e_6 = csr[j + 6];
        unsigned e_7 = csr[j + 7];
        GS32_LOAD(e_0, r0); GS32_LOAD(e_1, r1); GS32_LOAD(e_2, r2); GS32_LOAD(e_3, r3);
        GS32_LOAD(e_4, r4); GS32_LOAD(e_5, r5); GS32_LOAD(e_6, r6); GS32_LOAD(e_7, r7);
        GS32_ACC(r0, dec_nm(e_0)); GS32_ACC(r1, dec_nm(e_1));
        GS32_ACC(r2, dec_nm(e_2)); GS32_ACC(r3, dec_nm(e_3));
        GS32_ACC(r4, dec_nm(e_4)); GS32_ACC(r5, dec_nm(e_5));
        GS32_ACC(r6, dec_nm(e_6)); GS32_ACC(r7, dec_nm(e_7));
    }
    for (; j < e1; ++j) {
        unsigned e = csr[j];
        GS32_LOAD(e, rr);
        GS32_ACC(rr, dec_nm(e));
    }
    {
        float di = dinv[node];
        float d2 = di * di;
        GS32_LOAD((unsigned)node << 16, rs);
        GS32_ACC(rs, d2);
    }
#undef GS32_LOAD
#undef GS32_ACC
    uint4 ov;
    unsigned* op4 = &ov.x;
    for (int j2 = 0; j2 < 4; ++j2) {
        __half2 p = __floats2half2_rn(acc[2 * j2], acc[2 * j2 + 1]);
        op4[j2] = *(unsigned*)&p;
    }
    *(uint4*)(aggs + (size_t)slice * ((size_t)n * 32) + (size_t)node * 32 + q * 8) = ov;
}

// ---------------------------------------------------------------------------
// Layer-2 matmul (VALU, K=64): 32 nodes/block, x+W staged in LDS.
// Writes fp16 table (node-major-32 slices) AND pools h2 into sums
// (residual decomposition: pool(h3+res) = pool(relu3) + pool(h2)).
__global__ __launch_bounds__(256) void k_mm2(
    const float* __restrict__ Xs, const float* __restrict__ W,
    const float* __restrict__ kA, const float* __restrict__ kB,
    const int* __restrict__ batch, float* __restrict__ sums,
    __half* __restrict__ outh, int n) {
    constexpr int K = 64;
    constexpr int KP = K + 4;
    __shared__ float xl[32 * KP];
    __shared__ float wl[K * 128];
    int base = blockIdx.x * 32;
    int tid = threadIdx.x;
    for (int i = tid; i < 32 * K / 4; i += 256) {
        int nl = i / (K / 4);
        int off4 = (i % (K / 4)) * 4;
        int node = base + nl;
        float4 v = {0.f, 0.f, 0.f, 0.f};
        if (node < n)
            v = *(const float4*)(Xs + (size_t)node * K + off4);
        *(float4*)(&xl[nl * KP + off4]) = v;
    }

    int ct = tid & 31;
    int ng = tid >> 5;
    int c4 = ct * 4;
    float4 acc[4];
#pragma unroll
    for (int i = 0; i < 4; ++i) acc[i] = make_float4(0.f, 0.f, 0.f, 0.f);

    {
        const float4* Wsrc = (const float4*)W;
        float4* wl4 = (float4*)wl;
#pragma unroll 1
        for (int i = tid; i < K * 32; i += 256) wl4[i] = Wsrc[i];
    }
    __syncthreads();

#pragma unroll 1
    for (int k4 = 0; k4 < K / 4; ++k4) {
        float4 wv0 = *(const float4*)(&wl[(k4 * 4 + 0) * 128 + c4]);
        float4 wv1 = *(const float4*)(&wl[(k4 * 4 + 1) * 128 + c4]);
        float4 wv2 = *(const float4*)(&wl[(k4 * 4 + 2) * 128 + c4]);
        float4 wv3 = *(const float4*)(&wl[(k4 * 4 + 3) * 128 + c4]);
#pragma unroll
        for (int i = 0; i < 4; ++i) {
            float4 xv = *(const float4*)(&xl[(ng * 4 + i) * KP + k4 * 4]);
            acc[i].x += xv.x * wv0.x; acc[i].y += xv.x * wv0.y;
            acc[i].z += xv.x * wv0.z; acc[i].w += xv.x * wv0.w;
            acc[i].x += xv.y * wv1.x; acc[i].y += xv.y * wv1.y;
            acc[i].z += xv.y * wv1.z; acc[i].w += xv.y * wv1.w;
            acc[i].x += xv.z * wv2.x; acc[i].y += xv.z * wv2.y;
            acc[i].z += xv.z * wv2.z; acc[i].w += xv.z * wv2.w;
            acc[i].x += xv.w * wv3.x; acc[i].y += xv.w * wv3.y;
            acc[i].z += xv.w * wv3.z; acc[i].w += xv.w * wv3.w;
        }
    }

    float4 ka = *(const float4*)(kA + c4);
    float4 kb = *(const float4*)(kB + c4);
    int bg[4];
#pragma unroll
    for (int i = 0; i < 4; ++i) {
        int node = base + ng * 4 + i;
        bg[i] = -1;
        if (node >= n) continue;
        float4 a = acc[i];
        float4 v;
        v.x = fmaxf(a.x * ka.x + kb.x, 0.f);
        v.y = fmaxf(a.y * ka.y + kb.y, 0.f);
        v.z = fmaxf(a.z * ka.z + kb.z, 0.f);
        v.w = fmaxf(a.w * ka.w + kb.w, 0.f);
        size_t slot = (size_t)(c4 >> 5) * ((size_t)n * 32) + (size_t)node * 32 + (c4 & 31);
        __half2 h01 = __floats2half2_rn(v.x, v.y);
        __half2 h23 = __floats2half2_rn(v.z, v.w);
        uint2 r;
        r.x = *(unsigned*)&h01;
        r.y = *(unsigned*)&h23;
        *(uint2*)(outh + slot) = r;
        acc[i] = v;                 // keep h2 for residual pooling
        bg[i] = batch[node];
    }
    // pool h2 (residual term) into sums
    __shared__ float pred[8][128];
    int g0 = batch[base];
    int gl = batch[(base + 31 < n) ? (base + 31) : (n - 1)];
    for (int g = g0; g <= gl; ++g) {
        float4 s = make_float4(0.f, 0.f, 0.f, 0.f);
#pragma unroll
        for (int i = 0; i < 4; ++i) {
            if (bg[i] == g) {
                s.x += acc[i].x; s.y += acc[i].y;
                s.z += acc[i].z; s.w += acc[i].w;
            }
        }
        __syncthreads();
        *(float4*)(&pred[ng][c4]) = s;
        __syncthreads();
        if (ng < 4) {
            pred[ng][c4 + 0] += pred[ng + 4][c4 + 0];
            pred[ng][c4 + 1] += pred[ng + 4][c4 + 1];
            pred[ng][c4 + 2] += pred[ng + 4][c4 + 2];
            pred[ng][c4 + 3] += pred[ng + 4][c4 + 3];
        }
        __syncthreads();
        if (ng < 2) {
            pred[ng][c4 + 0] += pred[ng + 2][c4 + 0];
            pred[ng][c4 + 1] += pred[ng + 2][c4 + 1];
            pred[ng][c4 + 2] += pred[ng + 2][c4 + 2];
            pred[ng][c4 + 3] += pred[ng + 2][c4 + 3];
        }
        __syncthreads();
        if (ng == 0) {
            atomicAdd(&sums[g * 128 + c4 + 0], pred[0][c4 + 0] + pred[1][c4 + 0]);
            atomicAdd(&sums[g * 128 + c4 + 1], pred[0][c4 + 1] + pred[1][c4 + 1]);
            atomicAdd(&sums[g * 128 + c4 + 2], pred[0][c4 + 2] + pred[1][c4 + 2]);
            atomicAdd(&sums[g * 128 + c4 + 3], pred[0][c4 + 3] + pred[1][c4 + 3]);
        }
    }
}

// ---------------------------------------------------------------------------
// Layer-3 matmul via MFMA f16 (16x16x32): 64 nodes/block, 4 waves, wave =
// one 16-node m-tile x all 8 ch-tiles, K=128 in 4 steps. A-frags load
// directly from the gatherS32 fp16 table ([kstep][node][32] = lane row l&15,
// 8 contiguous k at (l>>4)*8). B-frags from pre-swizzled W3s. C/D mapping:
// col(ch)=lane&15, row(node)=(lane>>4)*4+reg [HW-verified]. BN+ReLU epilogue,
// then per-graph pooling of relu3 into sums (residual pooled by k_mm2).
__global__ __launch_bounds__(256) void k_mm3(
    const __half* __restrict__ aggs, const __half* __restrict__ W3s,
    const float* __restrict__ kA, const float* __restrict__ kB,
    const int* __restrict__ batch, float* __restrict__ sums, int n) {
    const size_t N32 = (size_t)n * 32;
    int base = blockIdx.x * 64;
    int tid = threadIdx.x;
    int w = tid >> 6;
    int l = tid & 63;
    int lr = l & 15;
    int lg = l >> 4;
    // A-fragments (clamped load: OOB rows only affect their own C rows,
    // which are excluded from pooling via bg=-1)
    int anode = base + w * 16 + lr;
    if (anode > n - 1) anode = n - 1;
    const __half* ap = aggs + (size_t)anode * 32 + lg * 8;
    f16x8 afr[4];
#pragma unroll
    for (int ks = 0; ks < 4; ++ks)
        afr[ks] = *(const f16x8*)(ap + (size_t)ks * N32);

    const f16x8* Wv = (const f16x8*)W3s;
    f32x4 acc[8];
#pragma unroll
    for (int nt = 0; nt < 8; ++nt) acc[nt] = (f32x4){0.f, 0.f, 0.f, 0.f};
#pragma unroll
    for (int nt = 0; nt < 8; ++nt) {
#pragma unroll
        for (int ks = 0; ks < 4; ++ks) {
            f16x8 bfr = Wv[(size_t)(nt * 4 + ks) * 64 + l];
            acc[nt] = __builtin_amdgcn_mfma_f32_16x16x32_f16(afr[ks], bfr, acc[nt], 0, 0, 0);
        }
    }
    // epilogue: BN + ReLU
    int pnode0 = base + w * 16 + lg * 4;
    int bgv[4];
#pragma unroll
    for (int r = 0; r < 4; ++r) {
        int nd = pnode0 + r;
        bgv[r] = (nd < n) ? batch[nd] : -1;
    }
    float h[8][4];
#pragma unroll
    for (int nt = 0; nt < 8; ++nt) {
        int ch = nt * 16 + lr;
        float ka = kA[ch], kb = kB[ch];
#pragma unroll
        for (int r = 0; r < 4; ++r)
            h[nt][r] = fmaxf(acc[nt][r] * ka + kb, 0.f);
    }
    // per-graph pooling
    __shared__ float pred[4][128];
    int g0 = batch[base];
    int gl = batch[(base + 63 < n) ? (base + 63) : (n - 1)];
    for (int g = g0; g <= gl; ++g) {
        __syncthreads();
#pragma unroll
        for (int nt = 0; nt < 8; ++nt) {
            float s = 0.f;
#pragma unroll
            for (int r = 0; r < 4; ++r)
                if (bgv[r] == g) s += h[nt][r];
            s += __shfl_xor(s, 16);
            s += __shfl_xor(s, 32);
            if (l < 16) pred[w][nt * 16 + l] = s;
        }
        __syncthreads();
        if (tid < 128) {
            float tot = pred[0][tid] + pred[1][tid] + pred[2][tid] + pred[3][tid];
            atomicAdd(&sums[g * 128 + tid], tot);
        }
    }
}

// ---------------------------------------------------------------------------
// Finalize: out[g] = dot(sums[g]/cnt[g], Wf) + bf. 256KB read — trivial.
__global__ __launch_bounds__(128) void k_final(
    const float* __restrict__ sums, const int* __restrict__ goffs,
    const float* __restrict__ Wf, const float* __restrict__ bf,
    float* __restrict__ out) {
    int g = blockIdx.x;
    int t = threadIdx.x;
    float v = sums[g * 128 + t] * Wf[t];
    for (int o = 32; o > 0; o >>= 1) v += __shfl_down(v, o);
    __shared__ float r[2];
    if (t == 0) r[0] = v;
    if (t == 64) r[1] = v;
    __syncthreads();
    if (t == 0) {
        int cnt = goffs[g + 1] - goffs[g];
        out[g] = (r[0] + r[1]) / fmaxf((float)cnt, 1.f) + bf[0];
    }
}

// ---------------------------------------------------------------------------
extern "C" void kernel_launch(void* const* d_in, const int* in_sizes, int n_in,
                              void* d_out, int out_size, void* d_ws, size_t ws_size,
                              hipStream_t stream) {
    const float* x     = (const float*)d_in[0];
    const int*   ei    = (const int*)d_in[1];
    const int*   src   = ei;
    const int*   dst   = ei + N_EDGES;
    const float* w     = (const float*)d_in[2];
    const int*   batch = (const int*)d_in[3];
    const float* W1 = (const float*)d_in[4];
    const float* b1 = (const float*)d_in[5];
    const float* W2 = (const float*)d_in[6];
    const float* b2 = (const float*)d_in[7];
    const float* W3 = (const float*)d_in[8];
    const float* b3 = (const float*)d_in[9];
    const float* Wf = (const float*)d_in[10];
    const float* bf = (const float*)d_in[11];
    const float* g1 = (const float*)d_in[12];
    const float* be1 = (const float*)d_in[13];
    const float* m1 = (const float*)d_in[14];
    const float* v1 = (const float*)d_in[15];
    const float* g2 = (const float*)d_in[16];
    const float* be2 = (const float*)d_in[17];
    const float* m2 = (const float*)d_in[18];
    const float* v2 = (const float*)d_in[19];
    const float* g3 = (const float*)d_in[20];
    const float* be3 = (const float*)d_in[21];
    const float* m3 = (const float*)d_in[22];
    const float* v3 = (const float*)d_in[23];

    float* out = (float*)d_out;

    // Workspace layout
    float* ws    = (float*)d_ws;
    float* buf2  = ws;                                    // N*128 region: agg2 fp32 then aggs fp16
    float* agg2  = buf2;
    unsigned* csr = (unsigned*)(buf2 + (size_t)N_NODES * 128); // E uint
    unsigned long long* packed = (unsigned long long*)(csr + N_EDGES); // N ull
    float* sums  = (float*)(packed + N_NODES);            // G*128
    unsigned long long* state = (unsigned long long*)(sums + N_GRAPHS * 128); // SCAN_NB ull
    unsigned* ticket = (unsigned*)(state + SCAN_NB);      // 4 uint (pad)
    int*   seq   = (int*)(ticket + 4);                    // E
    float* dinv  = (float*)(seq + N_EDGES);               // N
    float* aggx  = dinv + N_NODES;                        // N
    float* kA1   = aggx + N_NODES;                        // 64
    float* kB1   = kA1 + 64;                              // 64
    float* kA2   = kB1 + 64;                              // 128
    float* kB2   = kA2 + 128;                             // 128
    float* kA3   = kB2 + 128;                             // 128
    float* kB3   = kA3 + 128;                             // 128
    int*   offs  = (int*)(kB3 + 128);                     // N+1
    int*   goffs = offs + N_NODES + 1;                    // G+1 (+pad)
    // out2h: N*128 fp16 table, 64B-aligned so each 64B node-row is one line
    uintptr_t oh = (uintptr_t)(goffs + 505);
    oh = (oh + 63) & ~(uintptr_t)63;
    __half* out2h = (__half*)oh;                          // 12.8 MB
    __half* W3s   = out2h + (size_t)N_NODES * 128;        // 32 KB (64B-aligned)
    __half* aggsh = (__half*)buf2;                        // N*128 fp16 (over agg2, dead by then)

    const int BS = 256;
    auto nb = [](long n) { return (int)((n + 255) / 256); };

    // zero packed + sums + state + ticket in one call (contiguous in ws)
    size_t ms_bytes = (size_t)N_NODES * 8 + (size_t)N_GRAPHS * 128 * 4
                    + (size_t)SCAN_NB * 8 + 16;
    hipMemsetAsync(packed, 0, ms_bytes, stream);

    // --- CSR build + degree norm (+goffs+bnprep+W3 swizzle in scanF) ---
    k_degcnt<<<nb(N_EDGES), BS, 0, stream>>>(dst, w, packed, seq, N_EDGES);
    k_scanF<<<SCAN_NB, 256, 0, stream>>>(packed, state, ticket, offs, dinv, batch, goffs,
                                         W1, b1, g1, be1, m1, v1, b2, g2, be2, m2, v2,
                                         b3, g3, be3, m3, v3,
                                         kA1, kB1, kA2, kB2, kA3, kB3,
                                         W3, W3s, N_NODES);
    k_fill<<<nb(N_EDGES), BS, 0, stream>>>(src, dst, w, dinv, offs, seq, csr, N_EDGES);

    // --- Layer 1 aggregate (4 lanes/node) ---
    k_aggx<<<nb((long)N_NODES * 4), BS, 0, stream>>>(offs, csr, x, dinv, aggx, N_NODES);

    // --- Layer 2: fused L1-matmul + aggregate, then matmul -> fp16 table
    //     (+ residual pooling into sums) ---
    k_gather2F<<<nb((long)N_NODES * 16), BS, 0, stream>>>(
        offs, csr, aggx, dinv, kA1, kB1, agg2, N_NODES);
    k_mm2<<<(N_NODES + 31) / 32, BS, 0, stream>>>(
        agg2, W2, kA2, kB2, batch, sums, out2h, N_NODES);

    // --- Layer 3: sliced aggregate -> fp16 A-frag table, MFMA matmul + pool ---
    k_gatherS32<<<4 * ((N_NODES + 63) / 64), BS, 0, stream>>>(
        offs, csr, out2h, dinv, aggsh, N_NODES);
    k_mm3<<<(N_NODES + 63) / 64, BS, 0, stream>>>(
        aggsh, W3s, kA3, kB3, batch, sums, N_NODES);

    // --- finalize: tiny dot-product over sums ---
    k_final<<<N_GRAPHS, 128, 0, stream>>>(sums, goffs, Wf, bf, out);
}